// Round 11
// baseline (420.948 us; speedup 1.0000x reference)
//
#include <hip/hip_runtime.h>
#include <math.h>

// BagOfConcepts: inp [8,4096,512] f32, codebook [4096,512] f32
constexpr int D  = 512;
constexpr int K  = 4096;
constexpr int BM = 64;
constexpr int BN = 64;
constexpr int BD_LEG = 32;
constexpr int PAD = 4;

#define MARGIN 2.5e-3f     // >= W + 2E (deterministic bound); validated r6/r7/r8
constexpr int RCAP = 12;   // codes per (token,tile) record
constexpr unsigned CAPQ = 8388608u;   // queue capacity (fits ap region: 32 MB)

typedef short short8v __attribute__((ext_vector_type(8)));
typedef float f32x4   __attribute__((ext_vector_type(4)));

// ws layout (fast path)
constexpr size_t SC_OFF   = 0;                          // 4096 f32
constexpr size_t SX_OFF   = 16384;                      // 32768 f32
constexpr size_t KEYS_OFF = SX_OFF + 131072;            // 32768 u64 = 256 KB
constexpr size_t QCNT_OFF = KEYS_OFF + 262144;          // 1 u32 (+pad)
constexpr size_t CBP_OFF  = QCNT_OFF + 4096;            // 4096*512 u16 perm
constexpr size_t WS_NEED  = CBP_OFF + (size_t)K * D * 2;    // ~4.6 MB

__device__ inline unsigned short rne_bf16(float x) {
    unsigned u = __float_as_uint(x);
    return (unsigned short)((u + 0x7FFFu + ((u >> 16) & 1u)) >> 16);
}
__device__ inline unsigned ordkey(float f) {            // monotone f32 -> u32
    unsigned u = __float_as_uint(f);
    return (u & 0x80000000u) ? ~u : (u | 0x80000000u);
}
__device__ inline float fromkey(unsigned k) {
    unsigned u = (k & 0x80000000u) ? (k ^ 0x80000000u) : ~k;
    return __uint_as_float(u);
}
__device__ inline void gload16(const void* g, void* l) {
    __builtin_amdgcn_global_load_lds(
        (const __attribute__((address_space(1))) unsigned*)g,
        (__attribute__((address_space(3))) unsigned*)l, 16, 0, 0);
}

// ---------------- fused: sc (UNCHANGED arithmetic) + cvt_perm(cb) ----------------
// grid 1024: sc rows 4b..4b+3 ; cvt slots8 [256b, 256b+256)
__global__ __launch_bounds__(256)
void sccvt_kernel(const float* __restrict__ cb, float* __restrict__ sc,
                  unsigned short* __restrict__ cbp) {
    // part 1: sc (validated original body)
    {
        const int row  = blockIdx.x * 4 + (threadIdx.x >> 6);
        const int lane = threadIdx.x & 63;
        const float* r = cb + (size_t)row * D + lane * 8;
        float4 v0 = *(const float4*)r;
        float4 v1 = *(const float4*)(r + 4);
        float s = v0.x * v0.x;
        s += v0.y * v0.y; s += v0.z * v0.z; s += v0.w * v0.w;
        s += v1.x * v1.x; s += v1.y * v1.y; s += v1.z * v1.z; s += v1.w * v1.w;
#pragma unroll
        for (int off = 1; off < 64; off <<= 1) s += __shfl_xor(s, off, 64);
        if (lane == 0) sc[row] = s;
    }
    // part 2: cvt_perm for cb (validated original body)
    {
        const int s   = blockIdx.x * 256 + threadIdx.x;
        const int tile = s >> 13;
        const int db  = (s >> 9) & 15;
        const int j   = (s >> 7) & 3;
        const int row = s & 127;
        const float* sp = cb + (size_t)(tile * 128 + row) * D + db * 32 + j * 8;
        float4 v0 = *(const float4*)sp;
        float4 v1 = *(const float4*)(sp + 4);
        float xs[8] = {v0.x, v0.y, v0.z, v0.w, v1.x, v1.y, v1.z, v1.w};
        union { short8v v; unsigned short u[8]; } H;
#pragma unroll
        for (int i = 0; i < 8; ++i) H.u[i] = rne_bf16(xs[i]);
        *(short8v*)(cbp + (size_t)s * 8) = H.v;
    }
}

// ---------------- fused: sx (BIT-IDENTICAL fmaf chain) + cvt_perm(inp) ----------------
// grid tokens/64. Thread (r=t>>2, p=t&3) owns row m0+r cols [p*128, p*128+128):
// same 128-fmaf order as validated sx; cvt stores interleaved (independent ops).
__global__ __launch_bounds__(256)
void sxcvt_kernel(const float* __restrict__ inp, float* __restrict__ sxg,
                  unsigned short* __restrict__ ap) {
    const int t  = threadIdx.x;
    const int m0 = blockIdx.x * 64;
    const int r  = t >> 2, p = t & 3;
    const int row  = m0 + r;
    const int tile = row >> 7;
    const int rit  = row & 127;
    const float* rowp = inp + (size_t)row * D + p * 128;
    // dst slot8 = tile*8192 + (p*4 + (g>>2))*512 + (g&3)*128 + rit
    unsigned short* dbase = ap + ((size_t)tile * 8192 + (size_t)(p * 4) * 512 + rit) * 8;
    float s = 0.0f;
#pragma unroll
    for (int g = 0; g < 16; ++g) {
        float4 v0 = *(const float4*)(rowp + g * 8);
        float4 v1 = *(const float4*)(rowp + g * 8 + 4);
        s = fmaf(v0.x, v0.x, s); s = fmaf(v0.y, v0.y, s);
        s = fmaf(v0.z, v0.z, s); s = fmaf(v0.w, v0.w, s);
        s = fmaf(v1.x, v1.x, s); s = fmaf(v1.y, v1.y, s);
        s = fmaf(v1.z, v1.z, s); s = fmaf(v1.w, v1.w, s);
        float xs[8] = {v0.x, v0.y, v0.z, v0.w, v1.x, v1.y, v1.z, v1.w};
        union { short8v v; unsigned short u[8]; } H;
#pragma unroll
        for (int i = 0; i < 8; ++i) H.u[i] = rne_bf16(xs[i]);
        *(short8v*)(dbase + ((size_t)(g >> 2) * 512 + (size_t)(g & 3) * 128) * 8) = H.v;
    }
    s += __shfl_xor(s, 1, 64);
    s += __shfl_xor(s, 2, 64);
    if (p == 0) sxg[row] = s;
}

// ---------------- exact sequential dot (bit-identical to validated path) ----------------
__device__ float exact_dot512(const float* __restrict__ x, const float* __restrict__ c) {
    float s = 0.0f;
#pragma unroll 4
    for (int i = 0; i < 128; ++i) {
        const float4 xv = *(const float4*)(x + i * 4);
        const float4 cv = *(const float4*)(c + i * 4);
        s = fmaf(xv.x, cv.x, s); s = fmaf(xv.y, cv.y, s);
        s = fmaf(xv.z, cv.z, s); s = fmaf(xv.w, cv.w, s);
    }
    return s;
}

// ---------------- stage 1: 128x128 tile GEMM + per-tile argmin records ----------------
// r10: counted-vmcnt pipeline with the rule-#18 fix. Triple-buffered LDS, depth-2
// prefetch, fully-unrolled 16 chunks. sched_barrier(0) pins COMPUTE between the raw
// barriers (MFMA is register-only and crosses "memory" fences otherwise) and
// s_waitcnt lgkmcnt(0) before the trailing barrier guarantees no outstanding ds_read
// when the next chunk's DMA may overwrite the buffer (closes the r9 WAR race).
// Epilogue and record format UNCHANGED (validated r6/r7/r8).
__global__ __launch_bounds__(256)
void score_kernel(const unsigned short* __restrict__ a_perm,
                  const unsigned short* __restrict__ b_perm,
                  const float* __restrict__ sc,
                  char* __restrict__ records) {
    __shared__ __align__(16) unsigned short lds[3 * 8192];   // 48 KB: 3 bufs, A@+0 B@+4096
    __shared__ unsigned minsh[128];
    __shared__ unsigned cntsh[128];
    __shared__ unsigned short listsh[128][RCAP];

    const int t    = threadIdx.x;
    const int lane = t & 63;
    const int w    = t >> 6;
    const int wm   = w >> 1, wn = w & 1;
    const int l15  = lane & 15;
    const int lk   = lane >> 4;
    const int bm   = blockIdx.x >> 5;
    const int bn   = blockIdx.x & 31;

    const unsigned short* gA = a_perm + (size_t)bm * 65536 + (size_t)t * 8;
    const unsigned short* gB = b_perm + (size_t)bn * 65536 + (size_t)t * 8;

    if (t < 128) { minsh[t] = 0xFFFFFFFFu; cntsh[t] = 0u; }

    f32x4 acc[4][4];
#pragma unroll
    for (int i = 0; i < 4; ++i)
#pragma unroll
        for (int j = 0; j < 4; ++j) acc[i][j] = f32x4{0.f, 0.f, 0.f, 0.f};

    const unsigned short* lb = &lds[lk * 1024 + l15 * 8];
    const int mbase = wm * 512;
    const int nbase = 4096 + wn * 512;

#define STAGE(SOFF, DBUF)                                                          \
    gload16(gA + (SOFF),        &lds[(DBUF) + (0 * 256 + w * 64) * 8]);            \
    gload16(gA + (SOFF) + 2048, &lds[(DBUF) + (1 * 256 + w * 64) * 8]);            \
    gload16(gB + (SOFF),        &lds[(DBUF) + 4096 + (0 * 256 + w * 64) * 8]);     \
    gload16(gB + (SOFF) + 2048, &lds[(DBUF) + 4096 + (1 * 256 + w * 64) * 8]);

#define COMPUTE(CUR)                                                               \
    {                                                                              \
        short8v af[4], bf[4];                                                      \
        _Pragma("unroll")                                                          \
        for (int mt = 0; mt < 4; ++mt)                                             \
            af[mt] = *(const short8v*)(lb + (CUR) + mbase + mt * 128);             \
        _Pragma("unroll")                                                          \
        for (int nt = 0; nt < 4; ++nt)                                             \
            bf[nt] = *(const short8v*)(lb + (CUR) + nbase + nt * 128);             \
        _Pragma("unroll")                                                          \
        for (int mt = 0; mt < 4; ++mt)                                             \
            _Pragma("unroll")                                                      \
            for (int nt = 0; nt < 4; ++nt)                                         \
                acc[mt][nt] = __builtin_amdgcn_mfma_f32_16x16x32_bf16(             \
                    af[mt], bf[nt], acc[mt][nt], 0, 0, 0);                         \
    }

#define CHUNK(C, VM)                                                               \
    {                                                                              \
        if ((C) + 2 < 16) { STAGE((((C) + 2) * 4096), ((((C) + 2) % 3) * 8192)) }  \
        asm volatile("s_waitcnt vmcnt(" #VM ")" ::: "memory");                     \
        __builtin_amdgcn_s_barrier();                                              \
        __builtin_amdgcn_sched_barrier(0);                                         \
        COMPUTE((((C) % 3) * 8192))                                                \
        asm volatile("s_waitcnt lgkmcnt(0)" ::: "memory");                         \
        __builtin_amdgcn_sched_barrier(0);                                         \
        __builtin_amdgcn_s_barrier();                                              \
    }

    // prologue: chunks 0,1 in flight; retire chunk 0 (vmcnt(4)); lgkm drains minsh init
    STAGE(0, 0)
    STAGE(4096, 8192)
    asm volatile("s_waitcnt vmcnt(4) lgkmcnt(0)" ::: "memory");
    __builtin_amdgcn_s_barrier();
    __builtin_amdgcn_sched_barrier(0);

    CHUNK(0, 8)  CHUNK(1, 8)  CHUNK(2, 8)  CHUNK(3, 8)
    CHUNK(4, 8)  CHUNK(5, 8)  CHUNK(6, 8)  CHUNK(7, 8)
    CHUNK(8, 8)  CHUNK(9, 8)  CHUNK(10, 8) CHUNK(11, 8)
    CHUNK(12, 8) CHUNK(13, 8) CHUNK(14, 4) CHUNK(15, 0)

#undef CHUNK
#undef COMPUTE
#undef STAGE

    // ---- epilogue: UNCHANGED (validated) ----
    float scv[4];
#pragma unroll
    for (int nt = 0; nt < 4; ++nt) scv[nt] = sc[bn * 128 + wn * 64 + nt * 16 + l15];

#pragma unroll
    for (int mt = 0; mt < 4; ++mt)
#pragma unroll
        for (int nt = 0; nt < 4; ++nt)
#pragma unroll
            for (int r = 0; r < 4; ++r)
                acc[mt][nt][r] = fmaf(-2.0f, acc[mt][nt][r], scv[nt]);

#pragma unroll
    for (int mt = 0; mt < 4; ++mt)
#pragma unroll
        for (int r = 0; r < 4; ++r) {
            float m4 = fminf(fminf(acc[mt][0][r], acc[mt][1][r]),
                             fminf(acc[mt][2][r], acc[mt][3][r]));
            m4 = fminf(m4, __shfl_xor(m4, 1, 64));
            m4 = fminf(m4, __shfl_xor(m4, 2, 64));
            m4 = fminf(m4, __shfl_xor(m4, 4, 64));
            m4 = fminf(m4, __shfl_xor(m4, 8, 64));
            if (l15 == 0) {
                const int tok = wm * 64 + mt * 16 + lk * 4 + r;
                atomicMin(&minsh[tok], ordkey(m4));
            }
        }
    __syncthreads();

#pragma unroll
    for (int mt = 0; mt < 4; ++mt)
#pragma unroll
        for (int r = 0; r < 4; ++r) {
            const int tok = wm * 64 + mt * 16 + lk * 4 + r;
            const float tmn = fromkey(minsh[tok]) + MARGIN;
#pragma unroll
            for (int nt = 0; nt < 4; ++nt) {
                if (acc[mt][nt][r] <= tmn) {
                    unsigned p = atomicAdd(&cntsh[tok], 1u);
                    if (p < RCAP)
                        listsh[tok][p] = (unsigned short)(bn * 128 + wn * 64 + nt * 16 + l15);
                }
            }
        }
    __syncthreads();

    if (t < 128) {
        const unsigned* lw = (const unsigned*)&listsh[t][0];
        uint4 r0, r1;
        r0.x = __float_as_uint(fromkey(minsh[t]));
        r0.y = cntsh[t];
        r0.z = lw[0]; r0.w = lw[1];
        r1.x = lw[2]; r1.y = lw[3]; r1.z = lw[4]; r1.w = lw[5];
        char* rp = records + ((size_t)(bm * 128 + t) * 32 + bn) * 32;
        *(uint4*)rp = r0;
        *(uint4*)(rp + 16) = r1;
    }
}

// ---------------- stage 2a: compact candidates into a flat queue (UNCHANGED) ----------
__global__ __launch_bounds__(256)
void compact_kernel(const char* __restrict__ records,
                    unsigned long long* __restrict__ keysg,
                    unsigned* __restrict__ qcnt,
                    unsigned* __restrict__ queue) {
    const int token = blockIdx.x * 256 + threadIdx.x;
    keysg[token] = 0xFFFFFFFFFFFFFFFFull;

    const char* rbase = records + (size_t)token * 32 * 32;
    float mn = __builtin_huge_valf();
#pragma unroll
    for (int i = 0; i < 32; ++i)
        mn = fminf(mn, *(const float*)(rbase + (size_t)i * 32));
    const float thr = mn + MARGIN;

    unsigned my = 0;
#pragma unroll 1
    for (int i = 0; i < 32; ++i) {
        const char* rp = rbase + (size_t)i * 32;
        if (*(const float*)rp <= thr) {
            const unsigned cnt = *(const unsigned*)(rp + 4);
            my += (cnt <= RCAP) ? cnt : 128u;
        }
    }
    unsigned pos = atomicAdd(qcnt, my);
#pragma unroll 1
    for (int i = 0; i < 32; ++i) {
        const char* rp = rbase + (size_t)i * 32;
        if (*(const float*)rp <= thr) {
            const unsigned cnt = *(const unsigned*)(rp + 4);
            if (cnt <= RCAP) {
                const unsigned short* cs = (const unsigned short*)(rp + 8);
                for (unsigned j = 0; j < cnt; ++j) {
                    if (pos < CAPQ) queue[pos] = ((unsigned)token << 12) | cs[j];
                    ++pos;
                }
            } else {
                for (int c2 = 0; c2 < 128; ++c2) {
                    if (pos < CAPQ) queue[pos] = ((unsigned)token << 12) | (unsigned)(i * 128 + c2);
                    ++pos;
                }
            }
        }
    }
}

// ---------- stage 2b: exec — one lane per candidate, exact rescue (+fused safety) -----
__global__ __launch_bounds__(256)
void exec_kernel(const float* __restrict__ inp, const float* __restrict__ cb,
                 const float* __restrict__ sc, const float* __restrict__ sxg,
                 const unsigned* __restrict__ qcnt, const unsigned* __restrict__ queue,
                 unsigned long long* __restrict__ keysg, int nblk64) {
    const unsigned raw = *qcnt;
    unsigned total = raw > CAPQ ? CAPQ : raw;
    const unsigned stride = gridDim.x * 256;
    for (unsigned i = blockIdx.x * 256 + threadIdx.x; i < total; i += stride) {
        const unsigned e = queue[i];
        const int token = e >> 12;
        const int code  = e & 4095;
        const float dot = exact_dot512(inp + (size_t)token * D, cb + (size_t)code * D);
        const float tmp = sxg[token] - 2.0f * dot;   // -2*dot exact => contraction-immune
        const float v   = tmp + sc[code];
        const unsigned long long key =
            ((unsigned long long)__float_as_uint(v) << 32) | (unsigned)code;
        atomicMin(&keysg[token], key);
    }
    // fused safety: full exact scan iff queue overflowed (practically never)
    if (raw > CAPQ && blockIdx.x < (unsigned)nblk64) {
        const int t = threadIdx.x;
        const int m0 = blockIdx.x * 64;
#pragma unroll 1
        for (int tok = 0; tok < 64; ++tok) {
            const int token = m0 + tok;
            const float sxv = sxg[token];
            const float* xrow = inp + (size_t)token * D;
            for (int code = t; code < K; code += 256) {
                const float dot = exact_dot512(xrow, cb + (size_t)code * D);
                const float tmp = sxv - 2.0f * dot;
                const float v   = tmp + sc[code];
                const unsigned long long key =
                    ((unsigned long long)__float_as_uint(v) << 32) | (unsigned)code;
                atomicMin(&keysg[token], key);
            }
        }
    }
}

// ---------------- gather: bit-exact codebook row copy (UNCHANGED) ----------------------
__global__ __launch_bounds__(256)
void gather_kernel(const float* __restrict__ cb,
                   const unsigned long long* __restrict__ keysg,
                   float* __restrict__ out) {
    const int m0 = blockIdx.x * 64;
    __shared__ int bidx[64];
    if (threadIdx.x < 64) bidx[threadIdx.x] = (int)(keysg[m0 + threadIdx.x] & 0xFFFFFFFFull);
    __syncthreads();
    for (int q = threadIdx.x; q < 64 * (D / 4); q += 256) {
        const int r = q >> 7;
        const int c = (q & 127) * 4;
        *(float4*)(out + (size_t)(m0 + r) * D + c) = *(const float4*)(cb + (size_t)bidx[r] * D + c);
    }
}

// ================= LEGACY fallback path (round-1 validated) ==========
__global__ __launch_bounds__(256)
void sc_kernel(const float* __restrict__ cb, float* __restrict__ sc) {
    const int row  = blockIdx.x * 4 + (threadIdx.x >> 6);
    const int lane = threadIdx.x & 63;
    const float* r = cb + (size_t)row * D + lane * 8;
    float4 v0 = *(const float4*)r;
    float4 v1 = *(const float4*)(r + 4);
    float s = v0.x * v0.x;
    s += v0.y * v0.y; s += v0.z * v0.z; s += v0.w * v0.w;
    s += v1.x * v1.x; s += v1.y * v1.y; s += v1.z * v1.z; s += v1.w * v1.w;
#pragma unroll
    for (int off = 1; off < 64; off <<= 1) s += __shfl_xor(s, off, 64);
    if (lane == 0) sc[row] = s;
}

__global__ __launch_bounds__(256)
void vq_kernel(const float* __restrict__ inp, const float* __restrict__ cb,
               const float* __restrict__ sc, float* __restrict__ out) {
    __shared__ __align__(16) float As[BD_LEG][BM + PAD];
    __shared__ __align__(16) float Bs[BD_LEG][BN + PAD];
    __shared__ float sxl[BM];
    __shared__ float scs[BN];
    __shared__ int   bidx[BM];

    const int t  = threadIdx.x;
    const int m0 = blockIdx.x * BM;
    const int tm = t >> 4;
    const int tn = t & 15;
    const float FINF = __builtin_huge_valf();

    {
        const int r = t >> 2, p = t & 3;
        const float* row = inp + (size_t)(m0 + r) * D + p * 128;
        float s = 0.0f;
#pragma unroll
        for (int i = 0; i < 32; ++i) {
            float4 v = *(const float4*)(row + i * 4);
            s = fmaf(v.x, v.x, s); s = fmaf(v.y, v.y, s);
            s = fmaf(v.z, v.z, s); s = fmaf(v.w, v.w, s);
        }
        s += __shfl_xor(s, 1, 64);
        s += __shfl_xor(s, 2, 64);
        if (p == 0) sxl[r] = s;
    }
    __syncthreads();

    float sxm[4];
#pragma unroll
    for (int i = 0; i < 4; ++i) sxm[i] = sxl[tm * 4 + i];

    float runv[4] = {FINF, FINF, FINF, FINF};
    int   runi[4] = {0, 0, 0, 0};
    const int dq = (t & 7) << 2;
    const int mr = t >> 3;

#pragma unroll 1
    for (int kb = 0; kb < K; kb += BN) {
        __syncthreads();
        if (t < BN) scs[t] = sc[kb + t];

        float accl[4][4];
#pragma unroll
        for (int i = 0; i < 4; ++i)
#pragma unroll
            for (int j = 0; j < 4; ++j) accl[i][j] = 0.0f;

#pragma unroll 1
        for (int db = 0; db < D; db += BD_LEG) {
            const float* ap = inp + (size_t)(m0 + mr) * D + db + dq;
            const float* bp = cb  + (size_t)(kb + mr) * D + db + dq;
            float4 av0 = *(const float4*)ap;
            float4 av1 = *(const float4*)(ap + (size_t)32 * D);
            float4 bv0 = *(const float4*)bp;
            float4 bv1 = *(const float4*)(bp + (size_t)32 * D);
            __syncthreads();
            As[dq + 0][mr] = av0.x; As[dq + 1][mr] = av0.y;
            As[dq + 2][mr] = av0.z; As[dq + 3][mr] = av0.w;
            As[dq + 0][mr + 32] = av1.x; As[dq + 1][mr + 32] = av1.y;
            As[dq + 2][mr + 32] = av1.z; As[dq + 3][mr + 32] = av1.w;
            Bs[dq + 0][mr] = bv0.x; Bs[dq + 1][mr] = bv0.y;
            Bs[dq + 2][mr] = bv0.z; Bs[dq + 3][mr] = bv0.w;
            Bs[dq + 0][mr + 32] = bv1.x; Bs[dq + 1][mr + 32] = bv1.y;
            Bs[dq + 2][mr + 32] = bv1.z; Bs[dq + 3][mr + 32] = bv1.w;
            __syncthreads();
#pragma unroll
            for (int d = 0; d < BD_LEG; ++d) {
                const float4 a = *(const float4*)(&As[d][tm * 4]);
                const float4 b = *(const float4*)(&Bs[d][tn * 4]);
                float af[4] = {a.x, a.y, a.z, a.w};
                float bf[4] = {b.x, b.y, b.z, b.w};
#pragma unroll
                for (int i = 0; i < 4; ++i)
#pragma unroll
                    for (int j = 0; j < 4; ++j)
                        accl[i][j] = fmaf(af[i], bf[j], accl[i][j]);
            }
        }
#pragma unroll
        for (int i = 0; i < 4; ++i) {
            float bv = FINF;
            int   bi = 0x7fffffff;
#pragma unroll
            for (int j = 0; j < 4; ++j) {
                const float p = accl[i][j];
                const float tmp = sxm[i] - 2.0f * p;
                const float v   = tmp + scs[tn * 4 + j];
                const int  idx  = kb + tn * 4 + j;
                if (v < bv) { bv = v; bi = idx; }
            }
#pragma unroll
            for (int off = 1; off < 16; off <<= 1) {
                const float ov = __shfl_xor(bv, off, 64);
                const int   oi = __shfl_xor(bi, off, 64);
                if (ov < bv || (ov == bv && oi < bi)) { bv = ov; bi = oi; }
            }
            if (bv < runv[i]) { runv[i] = bv; runi[i] = bi; }
        }
    }
    if (tn == 0) {
#pragma unroll
        for (int i = 0; i < 4; ++i) bidx[tm * 4 + i] = runi[i];
    }
    __syncthreads();
#pragma unroll 1
    for (int q = t; q < BM * (D / 4); q += 256) {
        const int r = q >> 7;
        const int c = (q & 127) * 4;
        const float4 v = *(const float4*)(cb + (size_t)bidx[r] * D + c);
        *(float4*)(out + (size_t)(m0 + r) * D + c) = v;
    }
}

extern "C" void kernel_launch(void* const* d_in, const int* in_sizes, int n_in,
                              void* d_out, int out_size, void* d_ws, size_t ws_size,
                              hipStream_t stream) {
    const float* inp = (const float*)d_in[0];
    const float* cb  = (const float*)d_in[1];
    float* out = (float*)d_out;
    float* sc  = (float*)d_ws;
    const int tokens = in_sizes[0] / D;     // 32768

    const bool fast = (ws_size >= WS_NEED) && (tokens % 256 == 0) &&
                      (in_sizes[1] == K * D) &&
                      ((size_t)out_size * 4 >= (size_t)tokens * D * 2 + (size_t)tokens * 32 * 32);

    if (fast) {
        float* sxg = (float*)((char*)d_ws + SX_OFF);
        unsigned long long* keysg = (unsigned long long*)((char*)d_ws + KEYS_OFF);
        unsigned* qcnt = (unsigned*)((char*)d_ws + QCNT_OFF);
        unsigned short* cbp = (unsigned short*)((char*)d_ws + CBP_OFF);
        unsigned short* ap  = (unsigned short*)d_out;                       // 33.5 MB scratch
        char* records = (char*)d_out + (size_t)tokens * D * 2;              // 33.5 MB scratch
        unsigned* queue = (unsigned*)d_out;                                 // overlays ap (dead after score)

        hipMemsetAsync(qcnt, 0, sizeof(unsigned), stream);
        sccvt_kernel<<<K / 4, 256, 0, stream>>>(cb, sc, cbp);
        sxcvt_kernel<<<tokens / 64, 256, 0, stream>>>(inp, sxg, ap);
        score_kernel<<<(tokens / 128) * 32, 256, 0, stream>>>(ap, cbp, sc, records);
        compact_kernel<<<tokens / 256, 256, 0, stream>>>(records, keysg, qcnt, queue);
        exec_kernel<<<2048, 256, 0, stream>>>(inp, cb, sc, sxg, qcnt, queue, keysg, tokens / 64);
        gather_kernel<<<tokens / 64, 256, 0, stream>>>(cb, keysg, out);
    } else {
        sc_kernel<<<K / 4, 256, 0, stream>>>(cb, sc);
        vq_kernel<<<tokens / BM, 256, 0, stream>>>(inp, cb, sc, out);
    }
}

// Round 12
// 380.572 us; speedup vs baseline: 1.1061x; 1.1061x over previous
//
#include <hip/hip_runtime.h>
#include <math.h>

// BagOfConcepts: inp [8,4096,512] f32, codebook [4096,512] f32
constexpr int D  = 512;
constexpr int K  = 4096;
constexpr int BM = 64;
constexpr int BN = 64;
constexpr int BD_LEG = 32;
constexpr int PAD = 4;

#define MARGIN 2.5e-3f     // >= W + 2E (deterministic bound); validated r6/r7/r8/r11
constexpr int RCAP = 12;   // codes per (token,tile) record
constexpr unsigned CAPQ = 8388608u;   // queue capacity (fits ap region: 32 MB)

typedef short short8v __attribute__((ext_vector_type(8)));
typedef float f32x4   __attribute__((ext_vector_type(4)));

// ws layout (fast path)
constexpr size_t SC_OFF   = 0;                          // 4096 f32
constexpr size_t SX_OFF   = 16384;                      // 32768 f32
constexpr size_t KEYS_OFF = SX_OFF + 131072;            // 32768 u64 = 256 KB
constexpr size_t QCNT_OFF = KEYS_OFF + 262144;          // 1 u32 (+pad)
constexpr size_t CBP_OFF  = QCNT_OFF + 4096;            // 4096*512 u16 perm
constexpr size_t WS_NEED  = CBP_OFF + (size_t)K * D * 2;    // ~4.6 MB

__device__ inline unsigned short rne_bf16(float x) {
    unsigned u = __float_as_uint(x);
    return (unsigned short)((u + 0x7FFFu + ((u >> 16) & 1u)) >> 16);
}
__device__ inline unsigned ordkey(float f) {            // monotone f32 -> u32
    unsigned u = __float_as_uint(f);
    return (u & 0x80000000u) ? ~u : (u | 0x80000000u);
}
__device__ inline float fromkey(unsigned k) {
    unsigned u = (k & 0x80000000u) ? (k ^ 0x80000000u) : ~k;
    return __uint_as_float(u);
}
__device__ inline void gload16(const void* g, void* l) {
    __builtin_amdgcn_global_load_lds(
        (const __attribute__((address_space(1))) unsigned*)g,
        (__attribute__((address_space(3))) unsigned*)l, 16, 0, 0);
}

// ---------------- fused: sc (UNCHANGED arithmetic) + cvt_perm(cb) [validated r11] ------
__global__ __launch_bounds__(256)
void sccvt_kernel(const float* __restrict__ cb, float* __restrict__ sc,
                  unsigned short* __restrict__ cbp) {
    {
        const int row  = blockIdx.x * 4 + (threadIdx.x >> 6);
        const int lane = threadIdx.x & 63;
        const float* r = cb + (size_t)row * D + lane * 8;
        float4 v0 = *(const float4*)r;
        float4 v1 = *(const float4*)(r + 4);
        float s = v0.x * v0.x;
        s += v0.y * v0.y; s += v0.z * v0.z; s += v0.w * v0.w;
        s += v1.x * v1.x; s += v1.y * v1.y; s += v1.z * v1.z; s += v1.w * v1.w;
#pragma unroll
        for (int off = 1; off < 64; off <<= 1) s += __shfl_xor(s, off, 64);
        if (lane == 0) sc[row] = s;
    }
    {
        const int s   = blockIdx.x * 256 + threadIdx.x;
        const int tile = s >> 13;
        const int db  = (s >> 9) & 15;
        const int j   = (s >> 7) & 3;
        const int row = s & 127;
        const float* sp = cb + (size_t)(tile * 128 + row) * D + db * 32 + j * 8;
        float4 v0 = *(const float4*)sp;
        float4 v1 = *(const float4*)(sp + 4);
        float xs[8] = {v0.x, v0.y, v0.z, v0.w, v1.x, v1.y, v1.z, v1.w};
        union { short8v v; unsigned short u[8]; } H;
#pragma unroll
        for (int i = 0; i < 8; ++i) H.u[i] = rne_bf16(xs[i]);
        *(short8v*)(cbp + (size_t)s * 8) = H.v;
    }
}

// ---------------- fused: sx (BIT-IDENTICAL fmaf chain) + cvt_perm(inp) [validated r11] -
__global__ __launch_bounds__(256)
void sxcvt_kernel(const float* __restrict__ inp, float* __restrict__ sxg,
                  unsigned short* __restrict__ ap) {
    const int t  = threadIdx.x;
    const int m0 = blockIdx.x * 64;
    const int r  = t >> 2, p = t & 3;
    const int row  = m0 + r;
    const int tile = row >> 7;
    const int rit  = row & 127;
    const float* rowp = inp + (size_t)row * D + p * 128;
    unsigned short* dbase = ap + ((size_t)tile * 8192 + (size_t)(p * 4) * 512 + rit) * 8;
    float s = 0.0f;
#pragma unroll
    for (int g = 0; g < 16; ++g) {
        float4 v0 = *(const float4*)(rowp + g * 8);
        float4 v1 = *(const float4*)(rowp + g * 8 + 4);
        s = fmaf(v0.x, v0.x, s); s = fmaf(v0.y, v0.y, s);
        s = fmaf(v0.z, v0.z, s); s = fmaf(v0.w, v0.w, s);
        s = fmaf(v1.x, v1.x, s); s = fmaf(v1.y, v1.y, s);
        s = fmaf(v1.z, v1.z, s); s = fmaf(v1.w, v1.w, s);
        float xs[8] = {v0.x, v0.y, v0.z, v0.w, v1.x, v1.y, v1.z, v1.w};
        union { short8v v; unsigned short u[8]; } H;
#pragma unroll
        for (int i = 0; i < 8; ++i) H.u[i] = rne_bf16(xs[i]);
        *(short8v*)(dbase + ((size_t)(g >> 2) * 512 + (size_t)(g & 3) * 128) * 8) = H.v;
    }
    s += __shfl_xor(s, 1, 64);
    s += __shfl_xor(s, 2, 64);
    if (p == 0) sxg[row] = s;
}

// ---------------- exact sequential dot (bit-identical to validated path) ----------------
__device__ float exact_dot512(const float* __restrict__ x, const float* __restrict__ c) {
    float s = 0.0f;
#pragma unroll 4
    for (int i = 0; i < 128; ++i) {
        const float4 xv = *(const float4*)(x + i * 4);
        const float4 cv = *(const float4*)(c + i * 4);
        s = fmaf(xv.x, cv.x, s); s = fmaf(xv.y, cv.y, s);
        s = fmaf(xv.z, cv.z, s); s = fmaf(xv.w, cv.w, s);
    }
    return s;
}

// ---------------- stage 1: 128x128 tile GEMM + per-tile argmin records ----------------
// r12: EXACT r8 drain-loop structure (validated, 241us, 4 blocks/CU) + bijective
// XCD-chunked swizzle: each XCD owns contiguous (bm, all-bn) groups so cbp (4MB)
// stays L2-resident per XCD -> B staging becomes L2-hit latency.
// Epilogue and record format UNCHANGED (validated r6/r7/r8/r11).
__global__ __launch_bounds__(256)
void score_kernel(const unsigned short* __restrict__ a_perm,
                  const unsigned short* __restrict__ b_perm,
                  const float* __restrict__ sc,
                  char* __restrict__ records) {
    __shared__ __align__(16) unsigned short lds[16384];   // 32 KB: [buf:2][8192 halves]
    __shared__ unsigned minsh[128];
    __shared__ unsigned cntsh[128];
    __shared__ unsigned short listsh[128][RCAP];

    const int t    = threadIdx.x;
    const int lane = t & 63;
    const int w    = t >> 6;
    const int wm   = w >> 1, wn = w & 1;
    const int l15  = lane & 15;
    const int lk   = lane >> 4;
    // bijective XCD-chunked swizzle (nwg = 8192 = 8 * 1024): XCD x owns swz in
    // [x*1024, (x+1)*1024) = 32 consecutive bm-groups; within a group all 32 bn
    // share the A panel and sweep cbp (4MB = one XCD L2).
    const int bid  = blockIdx.x;
    const int swz  = (bid & 7) * 1024 + (bid >> 3);
    const int bm   = swz >> 5;
    const int bn   = swz & 31;

    // per-thread staging pointers (halves); chunk c at +c*4096, q=1 at +2048
    const unsigned short* gA = a_perm + (size_t)bm * 65536 + (size_t)t * 8;
    const unsigned short* gB = b_perm + (size_t)bn * 65536 + (size_t)t * 8;

    if (t < 128) { minsh[t] = 0xFFFFFFFFu; cntsh[t] = 0u; }

    f32x4 acc[4][4];
#pragma unroll
    for (int i = 0; i < 4; ++i)
#pragma unroll
        for (int j = 0; j < 4; ++j) acc[i][j] = f32x4{0.f, 0.f, 0.f, 0.f};

    // stage(soff in halves, dbuf in {0,8192}): 4x gload16, wave-uniform LDS base
    auto STAGE = [&](int soff, int dbuf) {
        gload16(gA + soff,        &lds[dbuf + (0 * 256 + w * 64) * 8]);
        gload16(gA + soff + 2048, &lds[dbuf + (1 * 256 + w * 64) * 8]);
        gload16(gB + soff,        &lds[dbuf + 4096 + (0 * 256 + w * 64) * 8]);
        gload16(gB + soff + 2048, &lds[dbuf + 4096 + (1 * 256 + w * 64) * 8]);
    };

    // prologue: chunk 0 -> buf0
    STAGE(0, 0);
    __syncthreads();

    // per-thread LDS read base; all 16 ds_read_b128 = base + compile-time immediate
    const unsigned short* lb = &lds[lk * 1024 + l15 * 8];
    const int mbase = wm * 512;           // wave-uniform
    const int nbase = 4096 + wn * 512;

    auto COMPUTE = [&](int cur) {
        short8v af[4], bf[4];
#pragma unroll
        for (int mt = 0; mt < 4; ++mt)
            af[mt] = *(const short8v*)(lb + cur + mbase + mt * 128);
#pragma unroll
        for (int nt = 0; nt < 4; ++nt)
            bf[nt] = *(const short8v*)(lb + cur + nbase + nt * 128);
#pragma unroll
        for (int mt = 0; mt < 4; ++mt)
#pragma unroll
            for (int nt = 0; nt < 4; ++nt)
                acc[mt][nt] = __builtin_amdgcn_mfma_f32_16x16x32_bf16(af[mt], bf[nt], acc[mt][nt], 0, 0, 0);
    };

    int soff = 4096;   // next chunk to stage = chunk 1
#pragma unroll 1
    for (int p = 0; p < 8; ++p) {
        // even sub-iter: compute buf0 (chunk 2p), stage chunk 2p+1 -> buf1
        STAGE(soff, 8192); soff += 4096;
        COMPUTE(0);
        __syncthreads();
        // odd sub-iter: compute buf1 (chunk 2p+1), stage chunk 2p+2 -> buf0 (skip last)
        if (p < 7) { STAGE(soff, 0); soff += 4096; }
        COMPUTE(8192);
        __syncthreads();
    }

    // ---- epilogue: UNCHANGED (validated) ----
    float scv[4];
#pragma unroll
    for (int nt = 0; nt < 4; ++nt) scv[nt] = sc[bn * 128 + wn * 64 + nt * 16 + l15];

#pragma unroll
    for (int mt = 0; mt < 4; ++mt)
#pragma unroll
        for (int nt = 0; nt < 4; ++nt)
#pragma unroll
            for (int r = 0; r < 4; ++r)
                acc[mt][nt][r] = fmaf(-2.0f, acc[mt][nt][r], scv[nt]);

#pragma unroll
    for (int mt = 0; mt < 4; ++mt)
#pragma unroll
        for (int r = 0; r < 4; ++r) {
            float m4 = fminf(fminf(acc[mt][0][r], acc[mt][1][r]),
                             fminf(acc[mt][2][r], acc[mt][3][r]));
            m4 = fminf(m4, __shfl_xor(m4, 1, 64));
            m4 = fminf(m4, __shfl_xor(m4, 2, 64));
            m4 = fminf(m4, __shfl_xor(m4, 4, 64));
            m4 = fminf(m4, __shfl_xor(m4, 8, 64));
            if (l15 == 0) {
                const int tok = wm * 64 + mt * 16 + lk * 4 + r;
                atomicMin(&minsh[tok], ordkey(m4));
            }
        }
    __syncthreads();

#pragma unroll
    for (int mt = 0; mt < 4; ++mt)
#pragma unroll
        for (int r = 0; r < 4; ++r) {
            const int tok = wm * 64 + mt * 16 + lk * 4 + r;
            const float tmn = fromkey(minsh[tok]) + MARGIN;
#pragma unroll
            for (int nt = 0; nt < 4; ++nt) {
                if (acc[mt][nt][r] <= tmn) {
                    unsigned p = atomicAdd(&cntsh[tok], 1u);
                    if (p < RCAP)
                        listsh[tok][p] = (unsigned short)(bn * 128 + wn * 64 + nt * 16 + l15);
                }
            }
        }
    __syncthreads();

    if (t < 128) {
        const unsigned* lw = (const unsigned*)&listsh[t][0];
        uint4 r0, r1;
        r0.x = __float_as_uint(fromkey(minsh[t]));
        r0.y = cntsh[t];
        r0.z = lw[0]; r0.w = lw[1];
        r1.x = lw[2]; r1.y = lw[3]; r1.z = lw[4]; r1.w = lw[5];
        char* rp = records + ((size_t)(bm * 128 + t) * 32 + bn) * 32;
        *(uint4*)rp = r0;
        *(uint4*)(rp + 16) = r1;
    }
}

// ---------------- stage 2a: compact candidates into a flat queue (UNCHANGED) ----------
__global__ __launch_bounds__(256)
void compact_kernel(const char* __restrict__ records,
                    unsigned long long* __restrict__ keysg,
                    unsigned* __restrict__ qcnt,
                    unsigned* __restrict__ queue) {
    const int token = blockIdx.x * 256 + threadIdx.x;
    keysg[token] = 0xFFFFFFFFFFFFFFFFull;

    const char* rbase = records + (size_t)token * 32 * 32;
    float mn = __builtin_huge_valf();
#pragma unroll
    for (int i = 0; i < 32; ++i)
        mn = fminf(mn, *(const float*)(rbase + (size_t)i * 32));
    const float thr = mn + MARGIN;

    unsigned my = 0;
#pragma unroll 1
    for (int i = 0; i < 32; ++i) {
        const char* rp = rbase + (size_t)i * 32;
        if (*(const float*)rp <= thr) {
            const unsigned cnt = *(const unsigned*)(rp + 4);
            my += (cnt <= RCAP) ? cnt : 128u;
        }
    }
    unsigned pos = atomicAdd(qcnt, my);
#pragma unroll 1
    for (int i = 0; i < 32; ++i) {
        const char* rp = rbase + (size_t)i * 32;
        if (*(const float*)rp <= thr) {
            const unsigned cnt = *(const unsigned*)(rp + 4);
            if (cnt <= RCAP) {
                const unsigned short* cs = (const unsigned short*)(rp + 8);
                for (unsigned j = 0; j < cnt; ++j) {
                    if (pos < CAPQ) queue[pos] = ((unsigned)token << 12) | cs[j];
                    ++pos;
                }
            } else {
                for (int c2 = 0; c2 < 128; ++c2) {
                    if (pos < CAPQ) queue[pos] = ((unsigned)token << 12) | (unsigned)(i * 128 + c2);
                    ++pos;
                }
            }
        }
    }
}

// ---------- stage 2b: exec — one lane per candidate, exact rescue (+fused safety) -----
__global__ __launch_bounds__(256)
void exec_kernel(const float* __restrict__ inp, const float* __restrict__ cb,
                 const float* __restrict__ sc, const float* __restrict__ sxg,
                 const unsigned* __restrict__ qcnt, const unsigned* __restrict__ queue,
                 unsigned long long* __restrict__ keysg, int nblk64) {
    const unsigned raw = *qcnt;
    unsigned total = raw > CAPQ ? CAPQ : raw;
    const unsigned stride = gridDim.x * 256;
    for (unsigned i = blockIdx.x * 256 + threadIdx.x; i < total; i += stride) {
        const unsigned e = queue[i];
        const int token = e >> 12;
        const int code  = e & 4095;
        const float dot = exact_dot512(inp + (size_t)token * D, cb + (size_t)code * D);
        const float tmp = sxg[token] - 2.0f * dot;   // -2*dot exact => contraction-immune
        const float v   = tmp + sc[code];
        const unsigned long long key =
            ((unsigned long long)__float_as_uint(v) << 32) | (unsigned)code;
        atomicMin(&keysg[token], key);
    }
    // fused safety: full exact scan iff queue overflowed (practically never)
    if (raw > CAPQ && blockIdx.x < (unsigned)nblk64) {
        const int t = threadIdx.x;
        const int m0 = blockIdx.x * 64;
#pragma unroll 1
        for (int tok = 0; tok < 64; ++tok) {
            const int token = m0 + tok;
            const float sxv = sxg[token];
            const float* xrow = inp + (size_t)token * D;
            for (int code = t; code < K; code += 256) {
                const float dot = exact_dot512(xrow, cb + (size_t)code * D);
                const float tmp = sxv - 2.0f * dot;
                const float v   = tmp + sc[code];
                const unsigned long long key =
                    ((unsigned long long)__float_as_uint(v) << 32) | (unsigned)code;
                atomicMin(&keysg[token], key);
            }
        }
    }
}

// ---------------- gather: bit-exact codebook row copy (UNCHANGED) ----------------------
__global__ __launch_bounds__(256)
void gather_kernel(const float* __restrict__ cb,
                   const unsigned long long* __restrict__ keysg,
                   float* __restrict__ out) {
    const int m0 = blockIdx.x * 64;
    __shared__ int bidx[64];
    if (threadIdx.x < 64) bidx[threadIdx.x] = (int)(keysg[m0 + threadIdx.x] & 0xFFFFFFFFull);
    __syncthreads();
    for (int q = threadIdx.x; q < 64 * (D / 4); q += 256) {
        const int r = q >> 7;
        const int c = (q & 127) * 4;
        *(float4*)(out + (size_t)(m0 + r) * D + c) = *(const float4*)(cb + (size_t)bidx[r] * D + c);
    }
}

// ================= LEGACY fallback path (round-1 validated) ==========
__global__ __launch_bounds__(256)
void sc_kernel(const float* __restrict__ cb, float* __restrict__ sc) {
    const int row  = blockIdx.x * 4 + (threadIdx.x >> 6);
    const int lane = threadIdx.x & 63;
    const float* r = cb + (size_t)row * D + lane * 8;
    float4 v0 = *(const float4*)r;
    float4 v1 = *(const float4*)(r + 4);
    float s = v0.x * v0.x;
    s += v0.y * v0.y; s += v0.z * v0.z; s += v0.w * v0.w;
    s += v1.x * v1.x; s += v1.y * v1.y; s += v1.z * v1.z; s += v1.w * v1.w;
#pragma unroll
    for (int off = 1; off < 64; off <<= 1) s += __shfl_xor(s, off, 64);
    if (lane == 0) sc[row] = s;
}

__global__ __launch_bounds__(256)
void vq_kernel(const float* __restrict__ inp, const float* __restrict__ cb,
               const float* __restrict__ sc, float* __restrict__ out) {
    __shared__ __align__(16) float As[BD_LEG][BM + PAD];
    __shared__ __align__(16) float Bs[BD_LEG][BN + PAD];
    __shared__ float sxl[BM];
    __shared__ float scs[BN];
    __shared__ int   bidx[BM];

    const int t  = threadIdx.x;
    const int m0 = blockIdx.x * BM;
    const int tm = t >> 4;
    const int tn = t & 15;
    const float FINF = __builtin_huge_valf();

    {
        const int r = t >> 2, p = t & 3;
        const float* row = inp + (size_t)(m0 + r) * D + p * 128;
        float s = 0.0f;
#pragma unroll
        for (int i = 0; i < 32; ++i) {
            float4 v = *(const float4*)(row + i * 4);
            s = fmaf(v.x, v.x, s); s = fmaf(v.y, v.y, s);
            s = fmaf(v.z, v.z, s); s = fmaf(v.w, v.w, s);
        }
        s += __shfl_xor(s, 1, 64);
        s += __shfl_xor(s, 2, 64);
        if (p == 0) sxl[r] = s;
    }
    __syncthreads();

    float sxm[4];
#pragma unroll
    for (int i = 0; i < 4; ++i) sxm[i] = sxl[tm * 4 + i];

    float runv[4] = {FINF, FINF, FINF, FINF};
    int   runi[4] = {0, 0, 0, 0};
    const int dq = (t & 7) << 2;
    const int mr = t >> 3;

#pragma unroll 1
    for (int kb = 0; kb < K; kb += BN) {
        __syncthreads();
        if (t < BN) scs[t] = sc[kb + t];

        float accl[4][4];
#pragma unroll
        for (int i = 0; i < 4; ++i)
#pragma unroll
            for (int j = 0; j < 4; ++j) accl[i][j] = 0.0f;

#pragma unroll 1
        for (int db = 0; db < D; db += BD_LEG) {
            const float* ap = inp + (size_t)(m0 + mr) * D + db + dq;
            const float* bp = cb  + (size_t)(kb + mr) * D + db + dq;
            float4 av0 = *(const float4*)ap;
            float4 av1 = *(const float4*)(ap + (size_t)32 * D);
            float4 bv0 = *(const float4*)bp;
            float4 bv1 = *(const float4*)(bp + (size_t)32 * D);
            __syncthreads();
            As[dq + 0][mr] = av0.x; As[dq + 1][mr] = av0.y;
            As[dq + 2][mr] = av0.z; As[dq + 3][mr] = av0.w;
            As[dq + 0][mr + 32] = av1.x; As[dq + 1][mr + 32] = av1.y;
            As[dq + 2][mr + 32] = av1.z; As[dq + 3][mr + 32] = av1.w;
            Bs[dq + 0][mr] = bv0.x; Bs[dq + 1][mr] = bv0.y;
            Bs[dq + 2][mr] = bv0.z; Bs[dq + 3][mr] = bv0.w;
            Bs[dq + 0][mr + 32] = bv1.x; Bs[dq + 1][mr + 32] = bv1.y;
            Bs[dq + 2][mr + 32] = bv1.z; Bs[dq + 3][mr + 32] = bv1.w;
            __syncthreads();
#pragma unroll
            for (int d = 0; d < BD_LEG; ++d) {
                const float4 a = *(const float4*)(&As[d][tm * 4]);
                const float4 b = *(const float4*)(&Bs[d][tn * 4]);
                float af[4] = {a.x, a.y, a.z, a.w};
                float bf[4] = {b.x, b.y, b.z, b.w};
#pragma unroll
                for (int i = 0; i < 4; ++i)
#pragma unroll
                    for (int j = 0; j < 4; ++j)
                        accl[i][j] = fmaf(af[i], bf[j], accl[i][j]);
            }
        }
#pragma unroll
        for (int i = 0; i < 4; ++i) {
            float bv = FINF;
            int   bi = 0x7fffffff;
#pragma unroll
            for (int j = 0; j < 4; ++j) {
                const float p = accl[i][j];
                const float tmp = sxm[i] - 2.0f * p;
                const float v   = tmp + scs[tn * 4 + j];
                const int  idx  = kb + tn * 4 + j;
                if (v < bv) { bv = v; bi = idx; }
            }
#pragma unroll
            for (int off = 1; off < 16; off <<= 1) {
                const float ov = __shfl_xor(bv, off, 64);
                const int   oi = __shfl_xor(bi, off, 64);
                if (ov < bv || (ov == bv && oi < bi)) { bv = ov; bi = oi; }
            }
            if (bv < runv[i]) { runv[i] = bv; runi[i] = bi; }
        }
    }
    if (tn == 0) {
#pragma unroll
        for (int i = 0; i < 4; ++i) bidx[tm * 4 + i] = runi[i];
    }
    __syncthreads();
#pragma unroll 1
    for (int q = t; q < BM * (D / 4); q += 256) {
        const int r = q >> 7;
        const int c = (q & 127) * 4;
        const float4 v = *(const float4*)(cb + (size_t)bidx[r] * D + c);
        *(float4*)(out + (size_t)(m0 + r) * D + c) = v;
    }
}

extern "C" void kernel_launch(void* const* d_in, const int* in_sizes, int n_in,
                              void* d_out, int out_size, void* d_ws, size_t ws_size,
                              hipStream_t stream) {
    const float* inp = (const float*)d_in[0];
    const float* cb  = (const float*)d_in[1];
    float* out = (float*)d_out;
    float* sc  = (float*)d_ws;
    const int tokens = in_sizes[0] / D;     // 32768

    const bool fast = (ws_size >= WS_NEED) && (tokens % 256 == 0) &&
                      (in_sizes[1] == K * D) &&
                      ((size_t)out_size * 4 >= (size_t)tokens * D * 2 + (size_t)tokens * 32 * 32);

    if (fast) {
        float* sxg = (float*)((char*)d_ws + SX_OFF);
        unsigned long long* keysg = (unsigned long long*)((char*)d_ws + KEYS_OFF);
        unsigned* qcnt = (unsigned*)((char*)d_ws + QCNT_OFF);
        unsigned short* cbp = (unsigned short*)((char*)d_ws + CBP_OFF);
        unsigned short* ap  = (unsigned short*)d_out;                       // 33.5 MB scratch
        char* records = (char*)d_out + (size_t)tokens * D * 2;              // 33.5 MB scratch
        unsigned* queue = (unsigned*)d_out;                                 // overlays ap (dead after score)

        hipMemsetAsync(qcnt, 0, sizeof(unsigned), stream);
        sccvt_kernel<<<K / 4, 256, 0, stream>>>(cb, sc, cbp);
        sxcvt_kernel<<<tokens / 64, 256, 0, stream>>>(inp, sxg, ap);
        score_kernel<<<(tokens / 128) * 32, 256, 0, stream>>>(ap, cbp, sc, records);
        compact_kernel<<<tokens / 256, 256, 0, stream>>>(records, keysg, qcnt, queue);
        exec_kernel<<<2048, 256, 0, stream>>>(inp, cb, sc, sxg, qcnt, queue, keysg, tokens / 64);
        gather_kernel<<<tokens / 64, 256, 0, stream>>>(cb, keysg, out);
    } else {
        sc_kernel<<<K / 4, 256, 0, stream>>>(cb, sc);
        vq_kernel<<<tokens / BM, 256, 0, stream>>>(inp, cb, sc, out);
    }
}

// Round 13
// 320.858 us; speedup vs baseline: 1.3119x; 1.1861x over previous
//
#include <hip/hip_runtime.h>
#include <math.h>

// BagOfConcepts: inp [8,4096,512] f32, codebook [4096,512] f32
constexpr int D  = 512;
constexpr int K  = 4096;
constexpr int BM = 64;
constexpr int BN = 64;
constexpr int BD_LEG = 32;
constexpr int PAD = 4;

#define MARGIN 2.5e-3f     // >= W + 2E (deterministic bound); validated r6-r12
constexpr int RCAP = 12;   // codes per (token,tile) record
constexpr unsigned CAPQ = 8388608u;   // queue capacity (fits ap region: 32 MB)

typedef short short8v __attribute__((ext_vector_type(8)));
typedef float f32x4   __attribute__((ext_vector_type(4)));

// ws layout (fast path)
constexpr size_t SC_OFF   = 0;                          // 4096 f32
constexpr size_t SX_OFF   = 16384;                      // 32768 f32
constexpr size_t KEYS_OFF = SX_OFF + 131072;            // 32768 u64 = 256 KB
constexpr size_t QCNT_OFF = KEYS_OFF + 262144;          // 1 u32 (+pad)
constexpr size_t CBP_OFF  = QCNT_OFF + 4096;            // 4096*512 u16 perm
constexpr size_t WS_NEED  = CBP_OFF + (size_t)K * D * 2;    // ~4.6 MB

__device__ inline unsigned short rne_bf16(float x) {
    unsigned u = __float_as_uint(x);
    return (unsigned short)((u + 0x7FFFu + ((u >> 16) & 1u)) >> 16);
}
__device__ inline unsigned ordkey(float f) {            // monotone f32 -> u32
    unsigned u = __float_as_uint(f);
    return (u & 0x80000000u) ? ~u : (u | 0x80000000u);
}
__device__ inline float fromkey(unsigned k) {
    unsigned u = (k & 0x80000000u) ? (k ^ 0x80000000u) : ~k;
    return __uint_as_float(u);
}
__device__ inline void gload16(const void* g, void* l) {
    __builtin_amdgcn_global_load_lds(
        (const __attribute__((address_space(1))) unsigned*)g,
        (__attribute__((address_space(3))) unsigned*)l, 16, 0, 0);
}

// ---------------- fused prep: {sc + cvt(cb, 256-row tiles)} | {sx + cvt(inp)} ---------
// blocks [0, nb_cb): sc rows 4b..4b+3 (validated body) + cbp slots [256b, 256b+256)
//   cbp slot8 s = [tile(16)][db(16)][j(4)][row(256)]; content cb[tile*256+row][db*32+j*8..+8]
// blocks [nb_cb, nb_cb+tokens/64): sxcvt (validated r11/r12 body, ap layout unchanged)
__global__ __launch_bounds__(256)
void prep_kernel(const float* __restrict__ cb, const float* __restrict__ inp,
                 float* __restrict__ sc, unsigned short* __restrict__ cbp,
                 float* __restrict__ sxg, unsigned short* __restrict__ ap,
                 int nb_cb) {
    const int t = threadIdx.x;
    if ((int)blockIdx.x < nb_cb) {
        {   // sc part (validated original body)
            const int row  = blockIdx.x * 4 + (t >> 6);
            const int lane = t & 63;
            const float* r = cb + (size_t)row * D + lane * 8;
            float4 v0 = *(const float4*)r;
            float4 v1 = *(const float4*)(r + 4);
            float s = v0.x * v0.x;
            s += v0.y * v0.y; s += v0.z * v0.z; s += v0.w * v0.w;
            s += v1.x * v1.x; s += v1.y * v1.y; s += v1.z * v1.z; s += v1.w * v1.w;
#pragma unroll
            for (int off = 1; off < 64; off <<= 1) s += __shfl_xor(s, off, 64);
            if (lane == 0) sc[row] = s;
        }
        {   // cvt cb -> 256-row-tile layout
            const int s   = blockIdx.x * 256 + t;
            const int tile = s >> 14;
            const int db  = (s >> 10) & 15;
            const int j   = (s >> 8) & 3;
            const int row = s & 255;
            const float* sp = cb + (size_t)(tile * 256 + row) * D + db * 32 + j * 8;
            float4 v0 = *(const float4*)sp;
            float4 v1 = *(const float4*)(sp + 4);
            float xs[8] = {v0.x, v0.y, v0.z, v0.w, v1.x, v1.y, v1.z, v1.w};
            union { short8v v; unsigned short u[8]; } H;
#pragma unroll
            for (int i = 0; i < 8; ++i) H.u[i] = rne_bf16(xs[i]);
            *(short8v*)(cbp + (size_t)s * 8) = H.v;
        }
    } else {
        // sxcvt (BIT-IDENTICAL fmaf chain; ap layout unchanged from validated r11/r12)
        const int m0 = ((int)blockIdx.x - nb_cb) * 64;
        const int r  = t >> 2, p = t & 3;
        const int row  = m0 + r;
        const int tile = row >> 7;
        const int rit  = row & 127;
        const float* rowp = inp + (size_t)row * D + p * 128;
        unsigned short* dbase = ap + ((size_t)tile * 8192 + (size_t)(p * 4) * 512 + rit) * 8;
        float s = 0.0f;
#pragma unroll
        for (int g = 0; g < 16; ++g) {
            float4 v0 = *(const float4*)(rowp + g * 8);
            float4 v1 = *(const float4*)(rowp + g * 8 + 4);
            s = fmaf(v0.x, v0.x, s); s = fmaf(v0.y, v0.y, s);
            s = fmaf(v0.z, v0.z, s); s = fmaf(v0.w, v0.w, s);
            s = fmaf(v1.x, v1.x, s); s = fmaf(v1.y, v1.y, s);
            s = fmaf(v1.z, v1.z, s); s = fmaf(v1.w, v1.w, s);
            float xs[8] = {v0.x, v0.y, v0.z, v0.w, v1.x, v1.y, v1.z, v1.w};
            union { short8v v; unsigned short u[8]; } H;
#pragma unroll
            for (int i = 0; i < 8; ++i) H.u[i] = rne_bf16(xs[i]);
            *(short8v*)(dbase + ((size_t)(g >> 2) * 512 + (size_t)(g & 3) * 128) * 8) = H.v;
        }
        s += __shfl_xor(s, 1, 64);
        s += __shfl_xor(s, 2, 64);
        if (p == 0) sxg[row] = s;
    }
}

// ---------------- exact sequential dot (bit-identical to validated path) ----------------
__device__ float exact_dot512(const float* __restrict__ x, const float* __restrict__ c) {
    float s = 0.0f;
#pragma unroll 4
    for (int i = 0; i < 128; ++i) {
        const float4 xv = *(const float4*)(x + i * 4);
        const float4 cv = *(const float4*)(c + i * 4);
        s = fmaf(xv.x, cv.x, s); s = fmaf(xv.y, cv.y, s);
        s = fmaf(xv.z, cv.z, s); s = fmaf(xv.w, cv.w, s);
    }
    return s;
}

// ---------------- stage 1: 128x256 tile GEMM + per-tile argmin records ----------------
// r13: r8 drain-loop structure (validated), geometry scaled to 128x256 / 512 thr (8
// waves, 2x4). Per chunk per wave: 8 ds_read_b128 + 16 MFMA (same as r8); staging 3
// gload16/thread; LDS 48KB dbuf -> 3 blocks/CU (24 waves). Blocks halve to 4096 ->
// prologue+epilogue amortized 2x. Records: 16 tiles of 256 codes per token.
__global__ __launch_bounds__(512)
void score_kernel(const unsigned short* __restrict__ a_perm,
                  const unsigned short* __restrict__ b_perm,
                  const float* __restrict__ sc,
                  char* __restrict__ records) {
    __shared__ __align__(16) unsigned short lds[2 * 12288];  // 48KB: A@+0(4096h) B@+4096(8192h)
    __shared__ unsigned minsh[128];
    __shared__ unsigned cntsh[128];
    __shared__ unsigned short listsh[128][RCAP];

    const int t    = threadIdx.x;
    const int lane = t & 63;
    const int w    = t >> 6;          // 0..7
    const int wm   = w >> 2;          // 0..1  (64-token row group)
    const int wn   = w & 3;           // 0..3  (64-code col group)
    const int l15  = lane & 15;
    const int lk   = lane >> 4;
    const int bm   = blockIdx.x >> 4; // 0..255
    const int bn   = blockIdx.x & 15; // 0..15

    // per-thread staging pointers (halves)
    const unsigned short* gA = a_perm + (size_t)bm * 65536  + (size_t)t * 8;   // 128 rows/tile
    const unsigned short* gB = b_perm + (size_t)bn * 131072 + (size_t)t * 8;   // 256 rows/tile

    if (t < 128) { minsh[t] = 0xFFFFFFFFu; cntsh[t] = 0u; }

    f32x4 acc[4][4];
#pragma unroll
    for (int i = 0; i < 4; ++i)
#pragma unroll
        for (int j = 0; j < 4; ++j) acc[i][j] = f32x4{0.f, 0.f, 0.f, 0.f};

    // stage one d-chunk: A 512 slot8 (1 call), B 1024 slot8 (2 calls); wave-uniform dests
    auto STAGE = [&](int sa, int sb, int dbuf) {
        gload16(gA + sa,        &lds[dbuf + (w * 64) * 8]);
        gload16(gB + sb,        &lds[dbuf + 4096 + (0 * 512 + w * 64) * 8]);
        gload16(gB + sb + 4096, &lds[dbuf + 4096 + (1 * 512 + w * 64) * 8]);
    };

    STAGE(0, 0, 0);
    __syncthreads();

    // LDS read bases: A j-stride 1024 halves, B j-stride 2048 halves
    const unsigned short* lbA = &lds[lk * 1024 + l15 * 8];
    const unsigned short* lbB = &lds[4096 + lk * 2048 + l15 * 8];
    const int mbase = wm * 512;   // wave-uniform (64 rows * 8 halves)
    const int nbase = wn * 512;

    auto COMPUTE = [&](int cur) {
        short8v af[4], bf[4];
#pragma unroll
        for (int mt = 0; mt < 4; ++mt)
            af[mt] = *(const short8v*)(lbA + cur + mbase + mt * 128);
#pragma unroll
        for (int nt = 0; nt < 4; ++nt)
            bf[nt] = *(const short8v*)(lbB + cur + nbase + nt * 128);
#pragma unroll
        for (int mt = 0; mt < 4; ++mt)
#pragma unroll
            for (int nt = 0; nt < 4; ++nt)
                acc[mt][nt] = __builtin_amdgcn_mfma_f32_16x16x32_bf16(af[mt], bf[nt], acc[mt][nt], 0, 0, 0);
    };

    int sa = 4096, sb = 8192;   // next chunk (halves offsets in gA/gB)
#pragma unroll 1
    for (int p = 0; p < 8; ++p) {
        STAGE(sa, sb, 12288); sa += 4096; sb += 8192;
        COMPUTE(0);
        __syncthreads();
        if (p < 7) { STAGE(sa, sb, 0); sa += 4096; sb += 8192; }
        COMPUTE(12288);
        __syncthreads();
    }

    // ---- epilogue (validated semantics; tile = 256 codes) ----
    float scv[4];
#pragma unroll
    for (int nt = 0; nt < 4; ++nt) scv[nt] = sc[bn * 256 + wn * 64 + nt * 16 + l15];

#pragma unroll
    for (int mt = 0; mt < 4; ++mt)
#pragma unroll
        for (int nt = 0; nt < 4; ++nt)
#pragma unroll
            for (int r = 0; r < 4; ++r)
                acc[mt][nt][r] = fmaf(-2.0f, acc[mt][nt][r], scv[nt]);

#pragma unroll
    for (int mt = 0; mt < 4; ++mt)
#pragma unroll
        for (int r = 0; r < 4; ++r) {
            float m4 = fminf(fminf(acc[mt][0][r], acc[mt][1][r]),
                             fminf(acc[mt][2][r], acc[mt][3][r]));
            m4 = fminf(m4, __shfl_xor(m4, 1, 64));
            m4 = fminf(m4, __shfl_xor(m4, 2, 64));
            m4 = fminf(m4, __shfl_xor(m4, 4, 64));
            m4 = fminf(m4, __shfl_xor(m4, 8, 64));
            if (l15 == 0) {
                const int tok = wm * 64 + mt * 16 + lk * 4 + r;
                atomicMin(&minsh[tok], ordkey(m4));
            }
        }
    __syncthreads();

#pragma unroll
    for (int mt = 0; mt < 4; ++mt)
#pragma unroll
        for (int r = 0; r < 4; ++r) {
            const int tok = wm * 64 + mt * 16 + lk * 4 + r;
            const float tmn = fromkey(minsh[tok]) + MARGIN;
#pragma unroll
            for (int nt = 0; nt < 4; ++nt) {
                if (acc[mt][nt][r] <= tmn) {
                    unsigned p = atomicAdd(&cntsh[tok], 1u);
                    if (p < RCAP)
                        listsh[tok][p] = (unsigned short)(bn * 256 + wn * 64 + nt * 16 + l15);
                }
            }
        }
    __syncthreads();

    if (t < 128) {
        const unsigned* lw = (const unsigned*)&listsh[t][0];
        uint4 r0, r1;
        r0.x = __float_as_uint(fromkey(minsh[t]));
        r0.y = cntsh[t];
        r0.z = lw[0]; r0.w = lw[1];
        r1.x = lw[2]; r1.y = lw[3]; r1.z = lw[4]; r1.w = lw[5];
        char* rp = records + ((size_t)(bm * 128 + t) * 16 + bn) * 32;
        *(uint4*)rp = r0;
        *(uint4*)(rp + 16) = r1;
    }
}

// ---------------- stage 2a: compact candidates into a flat queue (16 tiles) -----------
__global__ __launch_bounds__(256)
void compact_kernel(const char* __restrict__ records,
                    unsigned long long* __restrict__ keysg,
                    unsigned* __restrict__ qcnt,
                    unsigned* __restrict__ queue) {
    const int token = blockIdx.x * 256 + threadIdx.x;
    keysg[token] = 0xFFFFFFFFFFFFFFFFull;

    const char* rbase = records + (size_t)token * 16 * 32;
    float mn = __builtin_huge_valf();
#pragma unroll
    for (int i = 0; i < 16; ++i)
        mn = fminf(mn, *(const float*)(rbase + (size_t)i * 32));
    const float thr = mn + MARGIN;

    unsigned my = 0;
#pragma unroll 1
    for (int i = 0; i < 16; ++i) {
        const char* rp = rbase + (size_t)i * 32;
        if (*(const float*)rp <= thr) {
            const unsigned cnt = *(const unsigned*)(rp + 4);
            my += (cnt <= RCAP) ? cnt : 256u;
        }
    }
    unsigned pos = atomicAdd(qcnt, my);
#pragma unroll 1
    for (int i = 0; i < 16; ++i) {
        const char* rp = rbase + (size_t)i * 32;
        if (*(const float*)rp <= thr) {
            const unsigned cnt = *(const unsigned*)(rp + 4);
            if (cnt <= RCAP) {
                const unsigned short* cs = (const unsigned short*)(rp + 8);
                for (unsigned j = 0; j < cnt; ++j) {
                    if (pos < CAPQ) queue[pos] = ((unsigned)token << 12) | cs[j];
                    ++pos;
                }
            } else {
                for (int c2 = 0; c2 < 256; ++c2) {
                    if (pos < CAPQ) queue[pos] = ((unsigned)token << 12) | (unsigned)(i * 256 + c2);
                    ++pos;
                }
            }
        }
    }
}

// ---------- stage 2b: exec — one lane per candidate, exact rescue (+fused safety) -----
__global__ __launch_bounds__(256)
void exec_kernel(const float* __restrict__ inp, const float* __restrict__ cb,
                 const float* __restrict__ sc, const float* __restrict__ sxg,
                 const unsigned* __restrict__ qcnt, const unsigned* __restrict__ queue,
                 unsigned long long* __restrict__ keysg, int nblk64) {
    const unsigned raw = *qcnt;
    unsigned total = raw > CAPQ ? CAPQ : raw;
    const unsigned stride = gridDim.x * 256;
    for (unsigned i = blockIdx.x * 256 + threadIdx.x; i < total; i += stride) {
        const unsigned e = queue[i];
        const int token = e >> 12;
        const int code  = e & 4095;
        const float dot = exact_dot512(inp + (size_t)token * D, cb + (size_t)code * D);
        const float tmp = sxg[token] - 2.0f * dot;   // -2*dot exact => contraction-immune
        const float v   = tmp + sc[code];
        const unsigned long long key =
            ((unsigned long long)__float_as_uint(v) << 32) | (unsigned)code;
        atomicMin(&keysg[token], key);
    }
    // fused safety: full exact scan iff queue overflowed (practically never)
    if (raw > CAPQ && blockIdx.x < (unsigned)nblk64) {
        const int t = threadIdx.x;
        const int m0 = blockIdx.x * 64;
#pragma unroll 1
        for (int tok = 0; tok < 64; ++tok) {
            const int token = m0 + tok;
            const float sxv = sxg[token];
            const float* xrow = inp + (size_t)token * D;
            for (int code = t; code < K; code += 256) {
                const float dot = exact_dot512(xrow, cb + (size_t)code * D);
                const float tmp = sxv - 2.0f * dot;
                const float v   = tmp + sc[code];
                const unsigned long long key =
                    ((unsigned long long)__float_as_uint(v) << 32) | (unsigned)code;
                atomicMin(&keysg[token], key);
            }
        }
    }
}

// ---------------- gather: bit-exact codebook row copy (UNCHANGED) ----------------------
__global__ __launch_bounds__(256)
void gather_kernel(const float* __restrict__ cb,
                   const unsigned long long* __restrict__ keysg,
                   float* __restrict__ out) {
    const int m0 = blockIdx.x * 64;
    __shared__ int bidx[64];
    if (threadIdx.x < 64) bidx[threadIdx.x] = (int)(keysg[m0 + threadIdx.x] & 0xFFFFFFFFull);
    __syncthreads();
    for (int q = threadIdx.x; q < 64 * (D / 4); q += 256) {
        const int r = q >> 7;
        const int c = (q & 127) * 4;
        *(float4*)(out + (size_t)(m0 + r) * D + c) = *(const float4*)(cb + (size_t)bidx[r] * D + c);
    }
}

// ================= LEGACY fallback path (round-1 validated) ==========
__global__ __launch_bounds__(256)
void sc_kernel(const float* __restrict__ cb, float* __restrict__ sc) {
    const int row  = blockIdx.x * 4 + (threadIdx.x >> 6);
    const int lane = threadIdx.x & 63;
    const float* r = cb + (size_t)row * D + lane * 8;
    float4 v0 = *(const float4*)r;
    float4 v1 = *(const float4*)(r + 4);
    float s = v0.x * v0.x;
    s += v0.y * v0.y; s += v0.z * v0.z; s += v0.w * v0.w;
    s += v1.x * v1.x; s += v1.y * v1.y; s += v1.z * v1.z; s += v1.w * v1.w;
#pragma unroll
    for (int off = 1; off < 64; off <<= 1) s += __shfl_xor(s, off, 64);
    if (lane == 0) sc[row] = s;
}

__global__ __launch_bounds__(256)
void vq_kernel(const float* __restrict__ inp, const float* __restrict__ cb,
               const float* __restrict__ sc, float* __restrict__ out) {
    __shared__ __align__(16) float As[BD_LEG][BM + PAD];
    __shared__ __align__(16) float Bs[BD_LEG][BN + PAD];
    __shared__ float sxl[BM];
    __shared__ float scs[BN];
    __shared__ int   bidx[BM];

    const int t  = threadIdx.x;
    const int m0 = blockIdx.x * BM;
    const int tm = t >> 4;
    const int tn = t & 15;
    const float FINF = __builtin_huge_valf();

    {
        const int r = t >> 2, p = t & 3;
        const float* row = inp + (size_t)(m0 + r) * D + p * 128;
        float s = 0.0f;
#pragma unroll
        for (int i = 0; i < 32; ++i) {
            float4 v = *(const float4*)(row + i * 4);
            s = fmaf(v.x, v.x, s); s = fmaf(v.y, v.y, s);
            s = fmaf(v.z, v.z, s); s = fmaf(v.w, v.w, s);
        }
        s += __shfl_xor(s, 1, 64);
        s += __shfl_xor(s, 2, 64);
        if (p == 0) sxl[r] = s;
    }
    __syncthreads();

    float sxm[4];
#pragma unroll
    for (int i = 0; i < 4; ++i) sxm[i] = sxl[tm * 4 + i];

    float runv[4] = {FINF, FINF, FINF, FINF};
    int   runi[4] = {0, 0, 0, 0};
    const int dq = (t & 7) << 2;
    const int mr = t >> 3;

#pragma unroll 1
    for (int kb = 0; kb < K; kb += BN) {
        __syncthreads();
        if (t < BN) scs[t] = sc[kb + t];

        float accl[4][4];
#pragma unroll
        for (int i = 0; i < 4; ++i)
#pragma unroll
            for (int j = 0; j < 4; ++j) accl[i][j] = 0.0f;

#pragma unroll 1
        for (int db = 0; db < D; db += BD_LEG) {
            const float* ap = inp + (size_t)(m0 + mr) * D + db + dq;
            const float* bp = cb  + (size_t)(kb + mr) * D + db + dq;
            float4 av0 = *(const float4*)ap;
            float4 av1 = *(const float4*)(ap + (size_t)32 * D);
            float4 bv0 = *(const float4*)bp;
            float4 bv1 = *(const float4*)(bp + (size_t)32 * D);
            __syncthreads();
            As[dq + 0][mr] = av0.x; As[dq + 1][mr] = av0.y;
            As[dq + 2][mr] = av0.z; As[dq + 3][mr] = av0.w;
            As[dq + 0][mr + 32] = av1.x; As[dq + 1][mr + 32] = av1.y;
            As[dq + 2][mr + 32] = av1.z; As[dq + 3][mr + 32] = av1.w;
            Bs[dq + 0][mr] = bv0.x; Bs[dq + 1][mr] = bv0.y;
            Bs[dq + 2][mr] = bv0.z; Bs[dq + 3][mr] = bv0.w;
            Bs[dq + 0][mr + 32] = bv1.x; Bs[dq + 1][mr + 32] = bv1.y;
            Bs[dq + 2][mr + 32] = bv1.z; Bs[dq + 3][mr + 32] = bv1.w;
            __syncthreads();
#pragma unroll
            for (int d = 0; d < BD_LEG; ++d) {
                const float4 a = *(const float4*)(&As[d][tm * 4]);
                const float4 b = *(const float4*)(&Bs[d][tn * 4]);
                float af[4] = {a.x, a.y, a.z, a.w};
                float bf[4] = {b.x, b.y, b.z, b.w};
#pragma unroll
                for (int i = 0; i < 4; ++i)
#pragma unroll
                    for (int j = 0; j < 4; ++j)
                        accl[i][j] = fmaf(af[i], bf[j], accl[i][j]);
            }
        }
#pragma unroll
        for (int i = 0; i < 4; ++i) {
            float bv = FINF;
            int   bi = 0x7fffffff;
#pragma unroll
            for (int j = 0; j < 4; ++j) {
                const float p = accl[i][j];
                const float tmp = sxm[i] - 2.0f * p;
                const float v   = tmp + scs[tn * 4 + j];
                const int  idx  = kb + tn * 4 + j;
                if (v < bv) { bv = v; bi = idx; }
            }
#pragma unroll
            for (int off = 1; off < 16; off <<= 1) {
                const float ov = __shfl_xor(bv, off, 64);
                const int   oi = __shfl_xor(bi, off, 64);
                if (ov < bv || (ov == bv && oi < bi)) { bv = ov; bi = oi; }
            }
            if (bv < runv[i]) { runv[i] = bv; runi[i] = bi; }
        }
    }
    if (tn == 0) {
#pragma unroll
        for (int i = 0; i < 4; ++i) bidx[tm * 4 + i] = runi[i];
    }
    __syncthreads();
#pragma unroll 1
    for (int q = t; q < BM * (D / 4); q += 256) {
        const int r = q >> 7;
        const int c = (q & 127) * 4;
        const float4 v = *(const float4*)(cb + (size_t)bidx[r] * D + c);
        *(float4*)(out + (size_t)(m0 + r) * D + c) = v;
    }
}

extern "C" void kernel_launch(void* const* d_in, const int* in_sizes, int n_in,
                              void* d_out, int out_size, void* d_ws, size_t ws_size,
                              hipStream_t stream) {
    const float* inp = (const float*)d_in[0];
    const float* cb  = (const float*)d_in[1];
    float* out = (float*)d_out;
    float* sc  = (float*)d_ws;
    const int tokens = in_sizes[0] / D;     // 32768

    const bool fast = (ws_size >= WS_NEED) && (tokens % 256 == 0) &&
                      (in_sizes[1] == K * D) &&
                      ((size_t)out_size * 4 >= (size_t)tokens * D * 2 + (size_t)tokens * 16 * 32);

    if (fast) {
        float* sxg = (float*)((char*)d_ws + SX_OFF);
        unsigned long long* keysg = (unsigned long long*)((char*)d_ws + KEYS_OFF);
        unsigned* qcnt = (unsigned*)((char*)d_ws + QCNT_OFF);
        unsigned short* cbp = (unsigned short*)((char*)d_ws + CBP_OFF);
        unsigned short* ap  = (unsigned short*)d_out;                       // 32 MB scratch
        char* records = (char*)d_out + (size_t)tokens * D * 2;              // 16 MB scratch
        unsigned* queue = (unsigned*)d_out;                                 // overlays ap (dead after score)

        const int nb_cb = K / 4;   // 1024 == (K*D/8)/256 for D=512

        hipMemsetAsync(qcnt, 0, sizeof(unsigned), stream);
        prep_kernel<<<nb_cb + tokens / 64, 256, 0, stream>>>(cb, inp, sc, cbp, sxg, ap, nb_cb);
        score_kernel<<<(tokens / 128) * 16, 512, 0, stream>>>(ap, cbp, sc, records);
        compact_kernel<<<tokens / 256, 256, 0, stream>>>(records, keysg, qcnt, queue);
        exec_kernel<<<2048, 256, 0, stream>>>(inp, cb, sc, sxg, qcnt, queue, keysg, tokens / 64);
        gather_kernel<<<tokens / 64, 256, 0, stream>>>(cb, keysg, out);
    } else {
        sc_kernel<<<K / 4, 256, 0, stream>>>(cb, sc);
        vq_kernel<<<tokens / BM, 256, 0, stream>>>(inp, cb, sc, out);
    }
}